// Round 1
// baseline (288.070 us; speedup 1.0000x reference)
//
#include <hip/hip_runtime.h>

#define N_NODES  100000
#define N_EDGES  1600000
#define HIDDEN   128
#define N_GRAPHS 2048
#define VOCAB    28
#define NPAD     100352      // 392*256 padded node count (cnt/agg stride)

// ---------------------------------------------------------------------------
// k_zero: y_hat (2048 floats) + cnt[VOCAB][NPAD] + agg[NPAD] (contiguous ws
// region of 29*NPAD ints), all via int4 stores.
// 512 + 727552 = 728064 int4 -> 2844 blocks * 256.
// ---------------------------------------------------------------------------
__global__ __launch_bounds__(256) void k_zero(float* __restrict__ out,
                                              int* __restrict__ ws) {
    int i = blockIdx.x * 256 + threadIdx.x;
    if (i < N_GRAPHS / 4) {
        reinterpret_cast<int4*>(out)[i] = make_int4(0, 0, 0, 0);
    }
    int j = i - N_GRAPHS / 4;
    if (j >= 0 && j < (VOCAB + 1) * NPAD / 4) {
        reinterpret_cast<int4*>(ws)[j] = make_int4(0, 0, 0, 0);
    }
}

// ---------------------------------------------------------------------------
// k_prep: fold each layer's two linears into one. (unchanged)
// ---------------------------------------------------------------------------
__global__ __launch_bounds__(256) void k_prep(const float* __restrict__ w1_0,
                                              const float* __restrict__ w2_0,
                                              const float* __restrict__ b1_0,
                                              const float* __restrict__ b2_0,
                                              const float* __restrict__ w1_1,
                                              const float* __restrict__ b1_1,
                                              const float* __restrict__ w2_1,
                                              const float* __restrict__ b2_1,
                                              float* __restrict__ Wc0,
                                              float* __restrict__ bc0,
                                              float* __restrict__ wc1,
                                              float* __restrict__ bc1) {
    int t = threadIdx.x;
    if (blockIdx.x < 64) {
        int g = blockIdx.x * 256 + t;
        int i = g >> 7, j = g & 127;
        float s = 0.f;
#pragma unroll 8
        for (int k = 0; k < HIDDEN; ++k)
            s += w1_0[i * HIDDEN + k] * w2_0[k * HIDDEN + j];
        Wc0[g] = s;
    } else {
        if (t < 128) {
            float s = 0.f;
#pragma unroll 8
            for (int k = 0; k < HIDDEN; ++k)
                s += b1_0[k] * w2_0[k * HIDDEN + t];
            bc0[t] = s + b2_0[t];
            if (t == 0) {
                float q = 0.f;
                for (int k = 0; k < HIDDEN; ++k) q += b1_1[k] * w2_1[k];
                bc1[0] = q + b2_1[0];
            }
        } else {
            int i = t - 128;
            float s = 0.f;
#pragma unroll 8
            for (int k = 0; k < HIDDEN; ++k)
                s += w1_1[i * HIDDEN + k] * w2_1[k];
            wc1[i] = s;
        }
    }
}

// ---------------------------------------------------------------------------
// k_prep2: EW = embed @ Wc0   [28,128] (unchanged)
// ---------------------------------------------------------------------------
__global__ __launch_bounds__(256) void k_prep2(const float* __restrict__ embed,
                                               const float* __restrict__ Wc0,
                                               float* __restrict__ EW) {
    int g = blockIdx.x * 256 + threadIdx.x;
    if (g >= VOCAB * HIDDEN) return;
    int i = g >> 7, j = g & 127;
    float s = 0.f;
#pragma unroll 8
    for (int k = 0; k < HIDDEN; ++k)
        s += embed[i * HIDDEN + k] * Wc0[k * HIDDEN + j];
    EW[g] = s;
}

// ---------------------------------------------------------------------------
// k_sweep0: one pass over edges -> vocab count histogram per dst node.
// cnt layout transposed [VOCAB][NPAD] so k_layerA reads are lane-coalesced.
// 1.6M int atomics over 2.8M addresses: ~0.57 avg/address, near-zero
// contention. int4 edge loads, full occupancy (1563 blocks).
// ---------------------------------------------------------------------------
__global__ __launch_bounds__(256) void k_sweep0(const int4* __restrict__ esrc4,
                                                const int4* __restrict__ edst4,
                                                const int* __restrict__ x_idx,
                                                int* __restrict__ cnt) {
    int i = blockIdx.x * 256 + threadIdx.x;
    if (i >= N_EDGES / 4) return;
    int4 s = esrc4[i];
    int4 t = edst4[i];
    atomicAdd(&cnt[x_idx[s.x] * NPAD + t.x], 1);
    atomicAdd(&cnt[x_idx[s.y] * NPAD + t.y], 1);
    atomicAdd(&cnt[x_idx[s.z] * NPAD + t.z], 1);
    atomicAdd(&cnt[x_idx[s.w] * NPAD + t.w], 1);
}

// ---------------------------------------------------------------------------
// k_layerA: pure per-node compute, no edges, no LDS, no syncthreads.
//   h = sum_v (cnt_v + (v==xi)*(1+eps0)) * EW[v] + bc0
//   d[n] = dot(relu(h), wc1)
// EW/bc0/wc1 reads are wave-uniform (s_load); cnt reads lane-coalesced.
// ---------------------------------------------------------------------------
__global__ __launch_bounds__(256) void k_layerA(const int* __restrict__ cnt,
                                                const int* __restrict__ x_idx,
                                                const float* __restrict__ EW,
                                                const float* __restrict__ bc0,
                                                const float* __restrict__ wc1,
                                                const float* __restrict__ eps0,
                                                float* __restrict__ d) {
    const int n = blockIdx.x * 256 + threadIdx.x;
    const bool valid = (n < N_NODES);
    const int xi = valid ? x_idx[n] : 0;
    const float s = 1.0f + eps0[0];

    // counts -> float regs; fold the (1+eps0)*EW[xi] self-term into cf[xi].
    float cf[VOCAB];
#pragma unroll
    for (int v = 0; v < VOCAB; ++v) {
        float c = (float)cnt[v * NPAD + n];           // coalesced; padded rows are 0
        cf[v] = c + ((v == xi) ? s : 0.0f);
    }

    const float4* EW4 = reinterpret_cast<const float4*>(EW);   // uniform -> s_load
    const float4* b04 = reinterpret_cast<const float4*>(bc0);
    const float4* w14 = reinterpret_cast<const float4*>(wc1);

    float dacc = 0.f;
#pragma unroll 1
    for (int f4 = 0; f4 < 32; ++f4) {
        float4 a = b04[f4];
#pragma unroll
        for (int v = 0; v < VOCAB; ++v) {
            float4 e = EW4[v * 32 + f4];              // uniform -> s_load_dwordx4
            a.x += cf[v] * e.x;
            a.y += cf[v] * e.y;
            a.z += cf[v] * e.z;
            a.w += cf[v] * e.w;
        }
        float4 w = w14[f4];
        dacc += fmaxf(a.x, 0.f) * w.x + fmaxf(a.y, 0.f) * w.y
              + fmaxf(a.z, 0.f) * w.z + fmaxf(a.w, 0.f) * w.w;
    }
    if (valid) d[n] = dacc;
}

// ---------------------------------------------------------------------------
// k_sweep1: layer-1 aggregation: agg[dst] += d[src].
// d is 400 KB -> L2-resident gathers; 1.6M float atomics over 100k addresses
// (avg 16/address, spread across channels). Full occupancy.
// ---------------------------------------------------------------------------
__global__ __launch_bounds__(256) void k_sweep1(const int4* __restrict__ esrc4,
                                                const int4* __restrict__ edst4,
                                                const float* __restrict__ d,
                                                float* __restrict__ agg) {
    int i = blockIdx.x * 256 + threadIdx.x;
    if (i >= N_EDGES / 4) return;
    int4 s = esrc4[i];
    int4 t = edst4[i];
    atomicAdd(&agg[t.x], d[s.x]);
    atomicAdd(&agg[t.y], d[s.y]);
    atomicAdd(&agg[t.z], d[s.z]);
    atomicAdd(&agg[t.w], d[s.w]);
}

// ---------------------------------------------------------------------------
// k_final: r = (1+eps1)*d[n] + agg[n] + bc1; write x; fused graph segment-sum
// (batch is sorted -> per-block graph slice in LDS, one global atomic/graph).
// ---------------------------------------------------------------------------
__global__ __launch_bounds__(512) void k_final(const float* __restrict__ dvec,
                                               const float* __restrict__ agg,
                                               const int* __restrict__ batch,
                                               const float* __restrict__ eps1,
                                               const float* __restrict__ bc1,
                                               float* __restrict__ out) {
    __shared__ float gacc[N_GRAPHS];
    const int tid = threadIdx.x;
    const int n0 = blockIdx.x * 512;
    const int nlast = min(n0 + 511, N_NODES - 1);
    const int g0 = batch[n0];
    const int g1 = batch[nlast];
    for (int g = g0 + tid; g <= g1; g += 512) gacc[g] = 0.f;
    __syncthreads();

    int n = n0 + tid;
    if (n < N_NODES) {
        float r = (1.0f + eps1[0]) * dvec[n] + agg[n] + bc1[0];
        out[N_GRAPHS + n] = r;
        atomicAdd(&gacc[batch[n]], r);
    }
    __syncthreads();
    for (int g = g0 + tid; g <= g1; g += 512) {
        float v = gacc[g];
        if (v != 0.f) atomicAdd(&out[g], v);
    }
}

// ---------------------------------------------------------------------------
extern "C" void kernel_launch(void* const* d_in, const int* in_sizes, int n_in,
                              void* d_out, int out_size, void* d_ws, size_t ws_size,
                              hipStream_t stream) {
    const int*   x_idx = (const int*)d_in[0];
    const int*   esrc  = (const int*)d_in[1];
    const int*   edst  = (const int*)d_in[2];
    const int*   batch = (const int*)d_in[3];
    const float* embed = (const float*)d_in[4];
    const float* eps0  = (const float*)d_in[5];
    const float* w1_0  = (const float*)d_in[6];
    const float* b1_0  = (const float*)d_in[7];
    const float* w2_0  = (const float*)d_in[8];
    const float* b2_0  = (const float*)d_in[9];
    const float* eps1  = (const float*)d_in[10];
    const float* w1_1  = (const float*)d_in[11];
    const float* b1_1  = (const float*)d_in[12];
    const float* w2_1  = (const float*)d_in[13];
    const float* b2_1  = (const float*)d_in[14];

    float* out = (float*)d_out;

    // workspace: [cnt(VOCAB*NPAD) agg(NPAD) | d(N) | Wc0 | bc0 | wc1 | bc1 | EW]
    int*   cnt = (int*)d_ws;                          // VOCAB*NPAD (zeroed)
    float* agg = (float*)(cnt + VOCAB * NPAD);        // NPAD       (zeroed)
    float* d   = agg + NPAD;                          // N_NODES
    float* Wc0 = d + N_NODES;                         // 128*128
    float* bc0 = Wc0 + HIDDEN * HIDDEN;               // 128
    float* wc1 = bc0 + HIDDEN;                        // 128
    float* bc1 = wc1 + HIDDEN;                        // 1
    float* EW  = bc1 + 1;                             // 28*128

    // zero y_hat + cnt + agg : (2048/4 + 29*NPAD/4) int4 = 728064 -> 2844 blocks
    k_zero<<<2844, 256, 0, stream>>>(out, cnt);

    // fold weights, then EW
    k_prep<<<65, 256, 0, stream>>>(w1_0, w2_0, b1_0, b2_0, w1_1, b1_1, w2_1, b2_1,
                                   Wc0, bc0, wc1, bc1);
    k_prep2<<<(VOCAB * HIDDEN + 255) / 256, 256, 0, stream>>>(embed, Wc0, EW);

    // layer-0 histogram: one edge sweep of global int atomics
    k_sweep0<<<(N_EDGES / 4 + 255) / 256, 256, 0, stream>>>(
        (const int4*)esrc, (const int4*)edst, x_idx, cnt);

    // layer 0 (+dot wc1): pure per-node compute
    k_layerA<<<NPAD / 256, 256, 0, stream>>>(cnt, x_idx, EW, bc0, wc1, eps0, d);

    // layer-1 aggregation: one edge sweep of global float atomics
    k_sweep1<<<(N_EDGES / 4 + 255) / 256, 256, 0, stream>>>(
        (const int4*)esrc, (const int4*)edst, d, agg);

    // outputs: x + fused graph segment-sum
    k_final<<<NPAD / 512, 512, 0, stream>>>(d, agg, batch, eps1, bc1, out);
}

// Round 3
// 168.933 us; speedup vs baseline: 1.7052x; 1.7052x over previous
//
#include <hip/hip_runtime.h>

#define N_NODES  100000
#define N_EDGES  1600000
#define HIDDEN   128
#define N_GRAPHS 2048
#define VOCAB    28
#define NB       392        // dst buckets of 256 nodes (392*256 = 100352)
#define CAP      5000       // per-bucket edge capacity (E[cnt]=4096, sigma~64)
#define NBIN     512        // binning blocks
#define EPB      3125       // edges per binning block (512*3125 = 1.6M exact)
#define EPT      7          // ceil(3125/512) edges per thread
#define CSTR     29         // lcnt stride (gcd(29,32)=1 -> conflict-free)

// ---------------------------------------------------------------------------
// k_init: zero y_hat (2048) and gcursor (NB).
// ---------------------------------------------------------------------------
__global__ __launch_bounds__(256) void k_init(float* __restrict__ out,
                                              int* __restrict__ gcursor) {
    int i = blockIdx.x * 256 + threadIdx.x;
    if (i < N_GRAPHS) out[i] = 0.0f;
    else if (i < N_GRAPHS + NB) gcursor[i - N_GRAPHS] = 0;
}

// ---------------------------------------------------------------------------
// k_binprep: blocks [0,512): LDS multisplit of edges into NB dst-buckets.
//   packed edge: dl<<22 | x_idx[src]<<17 | src   (8+5+17 = 30 bits)
//   gcursor atomic issues before the reorder barrier; its return is consumed
//   only after the final barrier -> latency hidden under LDS scatter.
// blocks [512,519): T = embed @ w1_0   [28,128]
// block  519      : bc0 = b1_0@w2_0 + b2_0 ; wc1 = w1_1@w2_1 ; bc1
// ---------------------------------------------------------------------------
__global__ __launch_bounds__(512) void k_binprep(const int* __restrict__ esrc,
                                                 const int* __restrict__ edst,
                                                 const int* __restrict__ x_idx,
                                                 unsigned* __restrict__ binned,
                                                 int* __restrict__ gcursor,
                                                 const float* __restrict__ embed,
                                                 const float* __restrict__ w1_0,
                                                 const float* __restrict__ w2_0,
                                                 const float* __restrict__ b1_0,
                                                 const float* __restrict__ b2_0,
                                                 const float* __restrict__ w1_1,
                                                 const float* __restrict__ b1_1,
                                                 const float* __restrict__ w2_1,
                                                 const float* __restrict__ b2_1,
                                                 float* __restrict__ T,
                                                 float* __restrict__ bc0,
                                                 float* __restrict__ wc1,
                                                 float* __restrict__ bc1) {
    const int tid = threadIdx.x;
    const int bid = blockIdx.x;

    if (bid >= NBIN) {
        if (bid < NBIN + 7) {                       // T = embed @ w1_0
            int g = (bid - NBIN) * 512 + tid;       // < 3584
            int i = g >> 7, j = g & 127;
            float s = 0.f;
#pragma unroll 8
            for (int k = 0; k < HIDDEN; ++k)
                s += embed[i * HIDDEN + k] * w1_0[k * HIDDEN + j];
            T[g] = s;
        } else {                                    // bias / wc1 block
            if (tid < 128) {
                float s = 0.f;
#pragma unroll 8
                for (int k = 0; k < HIDDEN; ++k)
                    s += b1_0[k] * w2_0[k * HIDDEN + tid];
                bc0[tid] = s + b2_0[tid];
                if (tid == 0) {
                    float q = 0.f;
                    for (int k = 0; k < HIDDEN; ++k) q += b1_1[k] * w2_1[k];
                    bc1[0] = q + b2_1[0];
                }
            } else if (tid < 256) {
                int i = tid - 128;
                float s = 0.f;
#pragma unroll 8
                for (int k = 0; k < HIDDEN; ++k)
                    s += w1_1[i * HIDDEN + k] * w2_1[k];
                wc1[i] = s;
            }
        }
        return;
    }

    __shared__ int hist[512];
    __shared__ int scanbuf[512];
    __shared__ int lbase[512];
    __shared__ int lcur[512];
    __shared__ int gbase[512];
    __shared__ unsigned stage[EPB];
    __shared__ int tgt[EPB];        // packed (bucket<<12 | localrank)

    hist[tid] = 0;
    lcur[tid] = 0;
    __syncthreads();

    unsigned mypk[EPT];
    short    myb[EPT];
#pragma unroll
    for (int i = 0; i < EPT; ++i) {
        int idx = i * 512 + tid;
        myb[i] = -1;
        if (idx < EPB) {
            int e   = bid * EPB + idx;
            int dst = edst[e];
            int src = esrc[e];
            int b   = dst >> 8;
            int dl  = dst & 255;
            int vix = x_idx[src];
            mypk[i] = ((unsigned)dl << 22) | ((unsigned)vix << 17) | (unsigned)src;
            myb[i]  = (short)b;
            atomicAdd(&hist[b], 1);
        }
    }
    __syncthreads();

    int v = hist[tid];
    scanbuf[tid] = v;
    __syncthreads();
    for (int off = 1; off < 512; off <<= 1) {
        int x = (tid >= off) ? scanbuf[tid - off] : 0;
        __syncthreads();
        scanbuf[tid] += x;
        __syncthreads();
    }
    lbase[tid] = scanbuf[tid] - v;
    // issue global cursor atomics; result consumed only after final barrier
    if (tid < NB) gbase[tid] = (v > 0) ? atomicAdd(&gcursor[tid], v) : 0;
    __syncthreads();                 // REQUIRED: lbase[b] read cross-thread below

#pragma unroll
    for (int i = 0; i < EPT; ++i) {
        if (myb[i] >= 0) {
            int b   = myb[i];
            int pos = lbase[b] + atomicAdd(&lcur[b], 1);
            stage[pos] = mypk[i];
            tgt[pos]   = (b << 12) | (pos - lbase[b]);   // lr < 3125 < 4096
        }
    }
    __syncthreads();

    for (int i = tid; i < EPB; i += 512) {
        int u = tgt[i];
        int b = u >> 12, lr = u & 4095;
        binned[b * CAP + gbase[b] + lr] = stage[i];
    }
}

// ---------------------------------------------------------------------------
// k_prep2: EW = T @ w2_0   [28,128]
// ---------------------------------------------------------------------------
__global__ __launch_bounds__(512) void k_prep2(const float* __restrict__ T,
                                               const float* __restrict__ w2_0,
                                               float* __restrict__ EW) {
    int g = blockIdx.x * 512 + threadIdx.x;
    if (g >= VOCAB * HIDDEN) return;
    int i = g >> 7, j = g & 127;
    float s = 0.f;
#pragma unroll 8
    for (int k = 0; k < HIDDEN; ++k)
        s += T[i * HIDDEN + k] * w2_0[k * HIDDEN + j];
    EW[g] = s;
}

// ---------------------------------------------------------------------------
// k_layerC: one block per bucket of 256 nodes.
//   1) single scan of bucket edges -> LDS vocab histogram (stride-29)
//   2) lane = node: counts -> 28 float regs (STATIC indexing only; self-term
//      via (v==xi) select, no runtime register indexing -> no scratch),
//      then 32 float4 groups with wave-uniform EW/bc0/wc1 loads (s_load).
//   d[n] = dot(relu(sum_v cf_v*EW[v] + bc0), wc1)
// ---------------------------------------------------------------------------
__global__ __launch_bounds__(256) void k_layerC(const unsigned* __restrict__ binned,
                                                const int* __restrict__ gcursor,
                                                const int* __restrict__ x_idx,
                                                const float* __restrict__ EW,
                                                const float* __restrict__ bc0,
                                                const float* __restrict__ wc1,
                                                const float* __restrict__ eps0,
                                                float* __restrict__ d) {
    __shared__ int lcnt[256 * CSTR];    // 29.7 KB

    const int tid = threadIdx.x;
    const int b   = blockIdx.x;

    for (int i = tid; i < 256 * CSTR; i += 256) lcnt[i] = 0;
    __syncthreads();

    const int cnt = gcursor[b];
    const unsigned* bp = binned + (size_t)b * CAP;
    for (int i = tid; i < cnt; i += 256) {
        unsigned pk = bp[i];
        atomicAdd(&lcnt[(pk >> 22) * CSTR + ((pk >> 17) & 31)], 1);
    }
    __syncthreads();

    const int n      = b * 256 + tid;
    const bool valid = (n < N_NODES);
    const int xi     = valid ? x_idx[n] : 0;
    const float s    = 1.0f + eps0[0];

    float cf[VOCAB];
#pragma unroll
    for (int v = 0; v < VOCAB; ++v)
        cf[v] = (float)lcnt[tid * CSTR + v] + ((v == xi) ? s : 0.0f);

    const float4* EW4 = reinterpret_cast<const float4*>(EW);   // uniform
    const float4* b04 = reinterpret_cast<const float4*>(bc0);
    const float4* w14 = reinterpret_cast<const float4*>(wc1);

    float dacc = 0.f;
#pragma unroll 1
    for (int f4 = 0; f4 < 32; ++f4) {
        float4 a = b04[f4];
#pragma unroll
        for (int v = 0; v < VOCAB; ++v) {
            float4 e = EW4[v * 32 + f4];
            a.x += cf[v] * e.x;
            a.y += cf[v] * e.y;
            a.z += cf[v] * e.z;
            a.w += cf[v] * e.w;
        }
        float4 w = w14[f4];
        dacc += fmaxf(a.x, 0.f) * w.x + fmaxf(a.y, 0.f) * w.y
              + fmaxf(a.z, 0.f) * w.z + fmaxf(a.w, 0.f) * w.w;
    }
    if (valid) d[n] = dacc;
}

// ---------------------------------------------------------------------------
// k_B2: one block per bucket: layer-1 aggregation via LDS float atomics on
// racc[256] from L2-resident d[src] gathers. Fused x write + graph
// segment-sum (batch sorted -> per-block graph slice in LDS).
// ---------------------------------------------------------------------------
__global__ __launch_bounds__(256) void k_B2(const unsigned* __restrict__ binned,
                                            const int* __restrict__ gcursor,
                                            const float* __restrict__ d,
                                            const int* __restrict__ batch,
                                            const float* __restrict__ eps1,
                                            const float* __restrict__ bc1,
                                            float* __restrict__ out) {
    __shared__ float racc[256];
    __shared__ float gacc[N_GRAPHS];

    const int tid = threadIdx.x;
    const int b   = blockIdx.x;
    const int n0  = b * 256;
    if (n0 >= N_NODES) return;                     // uniform per block
    const int nlast = min(n0 + 255, N_NODES - 1);

    racc[tid] = 0.f;
    const int g0 = batch[n0];
    const int g1 = batch[nlast];
    for (int g = g0 + tid; g <= g1; g += 256) gacc[g] = 0.f;
    __syncthreads();

    const int cnt = gcursor[b];
    const unsigned* bp = binned + (size_t)b * CAP;
    for (int i = tid; i < cnt; i += 256) {
        unsigned pk = bp[i];
        atomicAdd(&racc[pk >> 22], d[pk & 0x1FFFFu]);
    }
    __syncthreads();

    int n = n0 + tid;
    if (n < N_NODES) {
        float r = (1.0f + eps1[0]) * d[n] + racc[tid] + bc1[0];
        out[N_GRAPHS + n] = r;
        atomicAdd(&gacc[batch[n]], r);
    }
    __syncthreads();
    for (int g = g0 + tid; g <= g1; g += 256) {
        float v = gacc[g];
        if (v != 0.f) atomicAdd(&out[g], v);
    }
}

// ---------------------------------------------------------------------------
extern "C" void kernel_launch(void* const* d_in, const int* in_sizes, int n_in,
                              void* d_out, int out_size, void* d_ws, size_t ws_size,
                              hipStream_t stream) {
    const int*   x_idx = (const int*)d_in[0];
    const int*   esrc  = (const int*)d_in[1];
    const int*   edst  = (const int*)d_in[2];
    const int*   batch = (const int*)d_in[3];
    const float* embed = (const float*)d_in[4];
    const float* eps0  = (const float*)d_in[5];
    const float* w1_0  = (const float*)d_in[6];
    const float* b1_0  = (const float*)d_in[7];
    const float* w2_0  = (const float*)d_in[8];
    const float* b2_0  = (const float*)d_in[9];
    const float* eps1  = (const float*)d_in[10];
    const float* w1_1  = (const float*)d_in[11];
    const float* b1_1  = (const float*)d_in[12];
    const float* w2_1  = (const float*)d_in[13];
    const float* b2_1  = (const float*)d_in[14];

    float* out = (float*)d_out;

    // workspace: [gcursor(512) | binned(NB*CAP) | d(100352) | T | bc0 | wc1 | bc1 | EW]
    int*      gcursor = (int*)d_ws;                           // NB (pad 512)
    unsigned* binned  = (unsigned*)(gcursor + 512);           // NB*CAP
    float*    d       = (float*)(binned + (size_t)NB * CAP);  // 100352
    float*    T       = d + 100352;                           // 28*128
    float*    bc0     = T + VOCAB * HIDDEN;                   // 128
    float*    wc1     = bc0 + HIDDEN;                         // 128
    float*    bc1     = wc1 + HIDDEN;                         // 1
    float*    EW      = bc1 + 1;                              // 28*128

    // zero y_hat + gcursor
    k_init<<<(N_GRAPHS + NB + 255) / 256, 256, 0, stream>>>(out, gcursor);

    // bin edges by dst bucket; fold weights in extra blocks (parallel)
    k_binprep<<<NBIN + 8, 512, 0, stream>>>(esrc, edst, x_idx, binned, gcursor,
                                            embed, w1_0, w2_0, b1_0, b2_0,
                                            w1_1, b1_1, w2_1, b2_1,
                                            T, bc0, wc1, bc1);

    // EW = T @ w2_0
    k_prep2<<<7, 512, 0, stream>>>(T, w2_0, EW);

    // layer 0 (+dot wc1): LDS count histogram + uniform-load FMA loop
    k_layerC<<<NB, 256, 0, stream>>>(binned, gcursor, x_idx, EW, bc0, wc1, eps0, d);

    // layer 1 aggregation in LDS + fused outputs
    k_B2<<<NB, 256, 0, stream>>>(binned, gcursor, d, batch, eps1, bc1, out);
}

// Round 4
// 164.782 us; speedup vs baseline: 1.7482x; 1.0252x over previous
//
#include <hip/hip_runtime.h>

#define N_NODES  100000
#define N_EDGES  1600000
#define HIDDEN   128
#define N_GRAPHS 2048
#define VOCAB    28
#define NB       256        // dst buckets of 392 nodes (256*392 = 100352)
#define NPB      392        // nodes per bucket
#define CAP      7000       // per-bucket capacity (E[cnt]=6250, sigma~79 -> +9.5σ)
#define NBIN     512        // binning blocks
#define EPB      3125       // edges per binning block (512*3125 = 1.6M exact)
#define EPT      4          // ceil(3125/1024)
#define CSTR     29         // lcnt stride (gcd(29,32)=1 -> conflict-free)
#define MAGIC    2804876602ULL  // ceil(2^40/392): b = (dst*MAGIC)>>40, exact for dst<2.8e5

// ---------------------------------------------------------------------------
// k_init: zero y_hat (2048) and gcursor (NB).
// ---------------------------------------------------------------------------
__global__ __launch_bounds__(256) void k_init(float* __restrict__ out,
                                              int* __restrict__ gcursor) {
    int i = blockIdx.x * 256 + threadIdx.x;
    if (i < N_GRAPHS) out[i] = 0.0f;
    else if (i < N_GRAPHS + NB) gcursor[i - N_GRAPHS] = 0;
}

// ---------------------------------------------------------------------------
// k_binprep: blocks [0,512): scan-free direct-scatter multisplit.
//   pass1: LDS hist[256] counts
//   reserve: gbase[b] = atomicAdd(&gcursor[b], hist[b])
//   pass2: lr = atomicAdd(&lcur[b],1); binned[b*CAP+gbase[b]+lr] = pk
//   packed edge: dl<<22 | x_idx[src]<<17 | src   (9+5+17 = 31 bits)
// blocks [512,516): T = embed @ w1_0 ; block 516: bc0/wc1/bc1 folds.
// ---------------------------------------------------------------------------
__global__ __launch_bounds__(1024) void k_binprep(const int* __restrict__ esrc,
                                                  const int* __restrict__ edst,
                                                  const int* __restrict__ x_idx,
                                                  unsigned* __restrict__ binned,
                                                  int* __restrict__ gcursor,
                                                  const float* __restrict__ embed,
                                                  const float* __restrict__ w1_0,
                                                  const float* __restrict__ w2_0,
                                                  const float* __restrict__ b1_0,
                                                  const float* __restrict__ b2_0,
                                                  const float* __restrict__ w1_1,
                                                  const float* __restrict__ b1_1,
                                                  const float* __restrict__ w2_1,
                                                  const float* __restrict__ b2_1,
                                                  float* __restrict__ T,
                                                  float* __restrict__ bc0,
                                                  float* __restrict__ wc1,
                                                  float* __restrict__ bc1) {
    const int tid = threadIdx.x;
    const int bid = blockIdx.x;

    if (bid >= NBIN) {
        if (bid < NBIN + 4) {                       // T = embed @ w1_0 [28,128]
            int g = (bid - NBIN) * 1024 + tid;
            if (g < VOCAB * HIDDEN) {
                int i = g >> 7, j = g & 127;
                float s = 0.f;
#pragma unroll 8
                for (int k = 0; k < HIDDEN; ++k)
                    s += embed[i * HIDDEN + k] * w1_0[k * HIDDEN + j];
                T[g] = s;
            }
        } else {                                    // bias / wc1 block
            if (tid < 128) {
                float s = 0.f;
#pragma unroll 8
                for (int k = 0; k < HIDDEN; ++k)
                    s += b1_0[k] * w2_0[k * HIDDEN + tid];
                bc0[tid] = s + b2_0[tid];
                if (tid == 0) {
                    float q = 0.f;
                    for (int k = 0; k < HIDDEN; ++k) q += b1_1[k] * w2_1[k];
                    bc1[0] = q + b2_1[0];
                }
            } else if (tid < 256) {
                int i = tid - 128;
                float s = 0.f;
#pragma unroll 8
                for (int k = 0; k < HIDDEN; ++k)
                    s += w1_1[i * HIDDEN + k] * w2_1[k];
                wc1[i] = s;
            }
        }
        return;
    }

    __shared__ int hist[NB];
    __shared__ int lcur[NB];
    __shared__ int gbase[NB];

    if (tid < NB) { hist[tid] = 0; lcur[tid] = 0; }
    __syncthreads();

    unsigned mypk[EPT];
    short    myb[EPT];
#pragma unroll
    for (int i = 0; i < EPT; ++i) {
        int idx = i * 1024 + tid;
        myb[i] = -1;
        if (idx < EPB) {
            int e   = bid * EPB + idx;
            int dst = edst[e];
            int src = esrc[e];
            int b   = (int)(((unsigned long long)dst * MAGIC) >> 40);
            int dl  = dst - b * NPB;
            int vix = x_idx[src];
            mypk[i] = ((unsigned)dl << 22) | ((unsigned)vix << 17) | (unsigned)src;
            myb[i]  = (short)b;
            atomicAdd(&hist[b], 1);
        }
    }
    __syncthreads();

    if (tid < NB) {
        int v = hist[tid];
        gbase[tid] = (v > 0) ? atomicAdd(&gcursor[tid], v) : 0;
    }
    __syncthreads();

#pragma unroll
    for (int i = 0; i < EPT; ++i) {
        if (myb[i] >= 0) {
            int b  = myb[i];
            int lr = atomicAdd(&lcur[b], 1);
            binned[(size_t)b * CAP + gbase[b] + lr] = mypk[i];
        }
    }
}

// ---------------------------------------------------------------------------
// k_prep2: EW = T @ w2_0   [28,128]
// ---------------------------------------------------------------------------
__global__ __launch_bounds__(1024) void k_prep2(const float* __restrict__ T,
                                                const float* __restrict__ w2_0,
                                                float* __restrict__ EW) {
    int g = blockIdx.x * 1024 + threadIdx.x;
    if (g >= VOCAB * HIDDEN) return;
    int i = g >> 7, j = g & 127;
    float s = 0.f;
#pragma unroll 8
    for (int k = 0; k < HIDDEN; ++k)
        s += T[i * HIDDEN + k] * w2_0[k * HIDDEN + j];
    EW[g] = s;
}

// ---------------------------------------------------------------------------
// k_layerC: one block (1024 thr) per bucket of 392 nodes, exactly 1/CU.
//   1) all 16 waves scan the bucket's edges -> LDS vocab histogram
//   2) lanes < 392: counts -> 28 float regs (static indexing; self-term via
//      (v==xi) select), then 32 float4 groups, wave-uniform EW/bc0/wc1 loads.
//   d[n] = dot(relu(sum_v cf_v*EW[v] + bc0), wc1)
// ---------------------------------------------------------------------------
__global__ __launch_bounds__(1024) void k_layerC(const unsigned* __restrict__ binned,
                                                 const int* __restrict__ gcursor,
                                                 const int* __restrict__ x_idx,
                                                 const float* __restrict__ EW,
                                                 const float* __restrict__ bc0,
                                                 const float* __restrict__ wc1,
                                                 const float* __restrict__ eps0,
                                                 float* __restrict__ d) {
    __shared__ int lcnt[NPB * CSTR];    // 45.5 KB

    const int tid = threadIdx.x;
    const int b   = blockIdx.x;

    for (int i = tid; i < NPB * CSTR; i += 1024) lcnt[i] = 0;
    __syncthreads();

    const int cnt = gcursor[b];
    const unsigned* bp = binned + (size_t)b * CAP;
    for (int i = tid; i < cnt; i += 1024) {
        unsigned pk = bp[i];
        atomicAdd(&lcnt[(pk >> 22) * CSTR + ((pk >> 17) & 31)], 1);
    }
    __syncthreads();

    if (tid >= NPB) return;

    const int n      = b * NPB + tid;
    const bool valid = (n < N_NODES);
    const int xi     = valid ? x_idx[n] : 0;
    const float s    = 1.0f + eps0[0];

    float cf[VOCAB];
#pragma unroll
    for (int v = 0; v < VOCAB; ++v)
        cf[v] = (float)lcnt[tid * CSTR + v] + ((v == xi) ? s : 0.0f);

    const float4* EW4 = reinterpret_cast<const float4*>(EW);   // uniform
    const float4* b04 = reinterpret_cast<const float4*>(bc0);
    const float4* w14 = reinterpret_cast<const float4*>(wc1);

    float dacc = 0.f;
#pragma unroll 1
    for (int f4 = 0; f4 < 32; ++f4) {
        float4 a = b04[f4];
#pragma unroll
        for (int v = 0; v < VOCAB; ++v) {
            float4 e = EW4[v * 32 + f4];
            a.x += cf[v] * e.x;
            a.y += cf[v] * e.y;
            a.z += cf[v] * e.z;
            a.w += cf[v] * e.w;
        }
        float4 w = w14[f4];
        dacc += fmaxf(a.x, 0.f) * w.x + fmaxf(a.y, 0.f) * w.y
              + fmaxf(a.z, 0.f) * w.z + fmaxf(a.w, 0.f) * w.w;
    }
    if (valid) d[n] = dacc;
}

// ---------------------------------------------------------------------------
// k_B2: one block (1024 thr) per bucket: layer-1 aggregation via LDS float
// atomics on racc[392] from L2-resident d[src] gathers. Fused x write +
// graph segment-sum (batch sorted -> per-block graph slice in LDS).
// ---------------------------------------------------------------------------
__global__ __launch_bounds__(1024) void k_B2(const unsigned* __restrict__ binned,
                                             const int* __restrict__ gcursor,
                                             const float* __restrict__ d,
                                             const int* __restrict__ batch,
                                             const float* __restrict__ eps1,
                                             const float* __restrict__ bc1,
                                             float* __restrict__ out) {
    __shared__ float racc[NPB];
    __shared__ float gacc[N_GRAPHS];

    const int tid = threadIdx.x;
    const int b   = blockIdx.x;
    const int n0  = b * NPB;
    const int nlast = min(n0 + NPB - 1, N_NODES - 1);

    if (tid < NPB) racc[tid] = 0.f;
    const int g0 = batch[n0];
    const int g1 = batch[nlast];
    for (int g = g0 + tid; g <= g1; g += 1024) gacc[g] = 0.f;
    __syncthreads();

    const int cnt = gcursor[b];
    const unsigned* bp = binned + (size_t)b * CAP;
    for (int i = tid; i < cnt; i += 1024) {
        unsigned pk = bp[i];
        atomicAdd(&racc[pk >> 22], d[pk & 0x1FFFFu]);
    }
    __syncthreads();

    int n = n0 + tid;
    if (tid < NPB && n < N_NODES) {
        float r = (1.0f + eps1[0]) * d[n] + racc[tid] + bc1[0];
        out[N_GRAPHS + n] = r;
        atomicAdd(&gacc[batch[n]], r);
    }
    __syncthreads();
    for (int g = g0 + tid; g <= g1; g += 1024) {
        float v = gacc[g];
        if (v != 0.f) atomicAdd(&out[g], v);
    }
}

// ---------------------------------------------------------------------------
extern "C" void kernel_launch(void* const* d_in, const int* in_sizes, int n_in,
                              void* d_out, int out_size, void* d_ws, size_t ws_size,
                              hipStream_t stream) {
    const int*   x_idx = (const int*)d_in[0];
    const int*   esrc  = (const int*)d_in[1];
    const int*   edst  = (const int*)d_in[2];
    const int*   batch = (const int*)d_in[3];
    const float* embed = (const float*)d_in[4];
    const float* eps0  = (const float*)d_in[5];
    const float* w1_0  = (const float*)d_in[6];
    const float* b1_0  = (const float*)d_in[7];
    const float* w2_0  = (const float*)d_in[8];
    const float* b2_0  = (const float*)d_in[9];
    const float* eps1  = (const float*)d_in[10];
    const float* w1_1  = (const float*)d_in[11];
    const float* b1_1  = (const float*)d_in[12];
    const float* w2_1  = (const float*)d_in[13];
    const float* b2_1  = (const float*)d_in[14];

    float* out = (float*)d_out;

    // workspace: [gcursor(512) | binned(NB*CAP) | d(100352) | T | bc0 | wc1 | bc1 | EW]
    int*      gcursor = (int*)d_ws;                           // NB (pad 512)
    unsigned* binned  = (unsigned*)(gcursor + 512);           // NB*CAP
    float*    d       = (float*)(binned + (size_t)NB * CAP);  // 100352
    float*    T       = d + 100352;                           // 28*128
    float*    bc0     = T + VOCAB * HIDDEN;                   // 128
    float*    wc1     = bc0 + HIDDEN;                         // 128
    float*    bc1     = wc1 + HIDDEN;                         // 1
    float*    EW      = bc1 + 1;                              // 28*128

    // zero y_hat + gcursor
    k_init<<<9, 256, 0, stream>>>(out, gcursor);

    // bin edges by dst bucket (scan-free); fold weights in extra blocks
    k_binprep<<<NBIN + 5, 1024, 0, stream>>>(esrc, edst, x_idx, binned, gcursor,
                                             embed, w1_0, w2_0, b1_0, b2_0,
                                             w1_1, b1_1, w2_1, b2_1,
                                             T, bc0, wc1, bc1);

    // EW = T @ w2_0
    k_prep2<<<4, 1024, 0, stream>>>(T, w2_0, EW);

    // layer 0 (+dot wc1): LDS count histogram + uniform-load FMA loop
    k_layerC<<<NB, 1024, 0, stream>>>(binned, gcursor, x_idx, EW, bc0, wc1, eps0, d);

    // layer 1 aggregation in LDS + fused outputs
    k_B2<<<NB, 1024, 0, stream>>>(binned, gcursor, d, batch, eps1, bc1, out);
}